// Round 8
// baseline (521.791 us; speedup 1.0000x reference)
//
#include <hip/hip_runtime.h>

// MaskedLoss: mean((roi*pred - roi*true)^2), roi = expanded bbox of mask fg.
// Shapes fixed by reference: [4,1,160,160,160] fp32/fp32/int32.
//
// 3 dispatches: ml_init (tiny) -> ml_bbox (mask scan, atomic bbox reduce)
//            -> ml_loss (weighted SSE + last-block final reduction).
//
// Layout: 160^3 = 4,096,000 voxels = 1,024,000 quads (16B) per batch;
// 6400 quads per d-slice, 40 quads per (d,h) row.
// Each thread handles 2 ADJACENT quads (32 B per array) per iteration.
// Grid-stride = 1000 blocks * 256 thr * 2 quads = 512,000 quads = EXACTLY
// 80 d-slices -> along the per-thread loop d advances by 80 and (h, w) are
// LOOP-INVARIANT: no divisions, no h/w tests in the hot loops.

namespace {
constexpr int BATCH = 4;
constexpr int DSZ = 160, HSZ = 160, WSZ = 160;
constexpr int SPATIAL = DSZ * HSZ * WSZ;      // 4,096,000
constexpr int QPB = SPATIAL / 4;              // 1,024,000 quads / batch
constexpr int NT = 256;                       // 4 waves / block
constexpr int PB = 1000;                      // blocks per batch (bbox & loss)
constexpr int STRIDE_Q = PB * NT * 2;         // 512,000 quads = 80 d-slices
constexpr int ITERS = QPB / STRIDE_Q;         // 2
constexpr int DSTEP = 80;                     // d advance per iteration
constexpr int NPART = BATCH * PB;             // 4000 partials
constexpr int TOTAL_BLOCKS = BATCH * PB;      // loss-kernel block count
constexpr int SENT_MIN = 1 << 30;

// ws layout (byte offsets)
constexpr int WS_NEG = 0;      // int [4][3]: max(axis_len-1 - min) per axis
constexpr int WS_MAX = 64;     // int [4][3]: max per axis
constexpr int WS_CNT = 128;    // int: last-block counter
constexpr int WS_PART = 256;   // float [NPART]
}

// clang vector types: __builtin_nontemporal_load requires these (HIP's
// int4/float4 are structs and are rejected).
typedef int   vint4   __attribute__((ext_vector_type(4)));
typedef float vfloat4 __attribute__((ext_vector_type(4)));

__device__ __forceinline__ vint4 ntload_i(const vint4* p) {
  return __builtin_nontemporal_load(p);
}
__device__ __forceinline__ vfloat4 ntload_f(const vfloat4* p) {
  return __builtin_nontemporal_load(p);
}

__device__ __forceinline__ int wred_min(int v) {
#pragma unroll
  for (int o = 32; o; o >>= 1) v = min(v, __shfl_xor(v, o));
  return v;
}
__device__ __forceinline__ int wred_max(int v) {
#pragma unroll
  for (int o = 32; o; o >>= 1) v = max(v, __shfl_xor(v, o));
  return v;
}

// ---------------- init: sentinels + counter ----------------
__global__ void ml_init(int* __restrict__ ws_i) {
  if (threadIdx.x == 0) {
#pragma unroll
    for (int k = 0; k < 12; ++k) ws_i[k] = -1;        // WS_NEG
#pragma unroll
    for (int k = 0; k < 12; ++k) ws_i[16 + k] = -1;   // WS_MAX
    ws_i[32] = 0;                                     // WS_CNT
  }
}

// ---------------- bbox: per-block fg bbox over mask, atomic global reduce ----------------
__global__ __launch_bounds__(NT) void ml_bbox(const int* __restrict__ mask,
                                              int* __restrict__ bneg,
                                              int* __restrict__ bmax) {
  const int b = blockIdx.y;
  const vint4* m4 = reinterpret_cast<const vint4*>(mask + (size_t)b * SPATIAL);

  const unsigned qb = (blockIdx.x * NT + threadIdx.x) * 2u;  // < 512000, even
  const unsigned d0 = qb / 6400u;
  const unsigned rem = qb - d0 * 6400u;                      // loop-invariant
  const unsigned h = rem / 40u;
  const int wb = (int)(rem - h * 40u) * 4;                   // 8 elems: wb..wb+7

  unsigned itermask = 0;  // bit i: any fg in iteration i (d = d0 + 80*i)
  int elemmask = 0;       // bit j: any fg at w = wb + j (any iteration), 8 bits
#pragma unroll
  for (int i = 0; i < ITERS; ++i) {
    vint4 v0 = ntload_i(&m4[qb + (size_t)i * STRIDE_Q]);
    vint4 v1 = ntload_i(&m4[qb + (size_t)i * STRIDE_Q + 1]);
    int e = (int)(v0[0] > 0) | ((int)(v0[1] > 0) << 1) |
            ((int)(v0[2] > 0) << 2) | ((int)(v0[3] > 0) << 3) |
            ((int)(v1[0] > 0) << 4) | ((int)(v1[1] > 0) << 5) |
            ((int)(v1[2] > 0) << 6) | ((int)(v1[3] > 0) << 7);
    elemmask |= e;
    itermask |= (e ? (1u << i) : 0u);
  }

  int dmin = SENT_MIN, dmax = -1, hmin = SENT_MIN, hmax = -1, wmin = SENT_MIN, wmax = -1;
  if (itermask) {
    int ifirst = __ffs(itermask) - 1;
    int ilast = 31 - __clz(itermask);
    dmin = (int)d0 + DSTEP * ifirst;
    dmax = (int)d0 + DSTEP * ilast;
    hmin = hmax = (int)h;
    wmin = wb + (__ffs(elemmask) - 1);
    wmax = wb + (31 - __clz(elemmask));
  }

  dmin = wred_min(dmin); dmax = wred_max(dmax);
  hmin = wred_min(hmin); hmax = wred_max(hmax);
  wmin = wred_min(wmin); wmax = wred_max(wmax);

  __shared__ int sred[4][6];
  const int wave = threadIdx.x >> 6, lane = threadIdx.x & 63;
  if (lane == 0) {
    sred[wave][0] = dmin; sred[wave][1] = dmax;
    sred[wave][2] = hmin; sred[wave][3] = hmax;
    sred[wave][4] = wmin; sred[wave][5] = wmax;
  }
  __syncthreads();
  if (threadIdx.x == 0) {
    int Dm = min(min(sred[0][0], sred[1][0]), min(sred[2][0], sred[3][0]));
    int DM = max(max(sred[0][1], sred[1][1]), max(sred[2][1], sred[3][1]));
    int Hm = min(min(sred[0][2], sred[1][2]), min(sred[2][2], sred[3][2]));
    int HM = max(max(sred[0][3], sred[1][3]), max(sred[2][3], sred[3][3]));
    int Wm = min(min(sred[0][4], sred[1][4]), min(sred[2][4], sred[3][4]));
    int WM = max(max(sred[0][5], sred[1][5]), max(sred[2][5], sred[3][5]));
    if (DM >= 0) {  // block saw some fg: device-scope atomic bbox reduce
      atomicMax(&bneg[b * 3 + 0], (DSZ - 1) - Dm);   // encodes min as max
      atomicMax(&bneg[b * 3 + 1], (HSZ - 1) - Hm);
      atomicMax(&bneg[b * 3 + 2], (WSZ - 1) - Wm);
      atomicMax(&bmax[b * 3 + 0], DM);
      atomicMax(&bmax[b * 3 + 1], HM);
      atomicMax(&bmax[b * 3 + 2], WM);
    }
  }
}

// replicate reference fp32 arithmetic exactly
__device__ __forceinline__ void axis_box(int mni, int mxi, int sh, int* lo_i, int* hi_i) {
  float mn = (float)mni, mx = (float)mxi;
  float c = (mx + mn) * 0.5f;
  float e = (mx - mn + 1.0f) * 0.5f * 1.2f;          // EXPAND = 1.2f
  float lo = fmaxf(0.0f, floorf(c - e));
  float hi = fminf((float)(sh - 1), floorf(c + e));  // hi is EXCLUSIVE bound
  *lo_i = (int)lo;
  *hi_i = (int)hi;
}

// ---------------- loss: weighted squared-diff + last-block final ----------------
__global__ __launch_bounds__(NT) void ml_loss(const float* __restrict__ pred,
                                              const float* __restrict__ tru,
                                              const int* __restrict__ bneg,
                                              const int* __restrict__ bmax,
                                              int* __restrict__ counter,
                                              float* __restrict__ partials,
                                              float* __restrict__ out) {
  const int b = blockIdx.y;

  // derive box params from the atomically-reduced bbox (cheap, per block)
  const int DM = bmax[b * 3 + 0], HM = bmax[b * 3 + 1], WM = bmax[b * 3 + 2];
  const int Dm = (DSZ - 1) - bneg[b * 3 + 0];
  const int Hm = (HSZ - 1) - bneg[b * 3 + 1];
  const int Wm = (WSZ - 1) - bneg[b * 3 + 2];
  int lod = 0, hid = 0, loh = 0, hih = 0, low = 0, hiw = 0;
  if (DM >= 0) {  // has fg; else empty box -> all weights 0.1
    axis_box(Dm, DM, DSZ, &lod, &hid);
    axis_box(Hm, HM, HSZ, &loh, &hih);
    axis_box(Wm, WM, WSZ, &low, &hiw);
  }

  const vfloat4* p4 = reinterpret_cast<const vfloat4*>(pred + (size_t)b * SPATIAL);
  const vfloat4* t4 = reinterpret_cast<const vfloat4*>(tru + (size_t)b * SPATIAL);

  const unsigned qb = (blockIdx.x * NT + threadIdx.x) * 2u;  // < 512000, even
  const unsigned d0 = qb / 6400u;
  const unsigned rem = qb - d0 * 6400u;                      // loop-invariant
  const unsigned h = rem / 40u;
  const int wb = (int)(rem - h * 40u) * 4;                   // 8 elems: wb..wb+7

  // fold (h,w) membership into 8 per-element weights; only the d test remains.
  const bool inh = ((int)h >= loh) & ((int)h < hih);
  float wgt[8];
#pragma unroll
  for (int j = 0; j < 8; ++j)
    wgt[j] = (inh & (wb + j >= low) & (wb + j < hiw)) ? 1.0f : 0.1f;

  float s0 = 0.0f, s1 = 0.0f, s2 = 0.0f, s3 = 0.0f;
#pragma unroll
  for (int i = 0; i < ITERS; ++i) {
    const size_t q = qb + (size_t)i * STRIDE_Q;
    vfloat4 pv0 = ntload_f(&p4[q]);
    vfloat4 pv1 = ntload_f(&p4[q + 1]);
    vfloat4 tv0 = ntload_f(&t4[q]);
    vfloat4 tv1 = ntload_f(&t4[q + 1]);
    const int d = (int)d0 + DSTEP * i;
    const bool ind = (d >= lod) & (d < hid);
    float r, a;
    r = ind ? wgt[0] : 0.1f; a = r * pv0[0] - r * tv0[0]; s0 = fmaf(a, a, s0);
    r = ind ? wgt[1] : 0.1f; a = r * pv0[1] - r * tv0[1]; s1 = fmaf(a, a, s1);
    r = ind ? wgt[2] : 0.1f; a = r * pv0[2] - r * tv0[2]; s2 = fmaf(a, a, s2);
    r = ind ? wgt[3] : 0.1f; a = r * pv0[3] - r * tv0[3]; s3 = fmaf(a, a, s3);
    r = ind ? wgt[4] : 0.1f; a = r * pv1[0] - r * tv1[0]; s0 = fmaf(a, a, s0);
    r = ind ? wgt[5] : 0.1f; a = r * pv1[1] - r * tv1[1]; s1 = fmaf(a, a, s1);
    r = ind ? wgt[6] : 0.1f; a = r * pv1[2] - r * tv1[2]; s2 = fmaf(a, a, s2);
    r = ind ? wgt[7] : 0.1f; a = r * pv1[3] - r * tv1[3]; s3 = fmaf(a, a, s3);
  }
  float s = (s0 + s1) + (s2 + s3);

#pragma unroll
  for (int o = 32; o; o >>= 1) s += __shfl_xor(s, o);
  __shared__ float ls[4];
  __shared__ bool amLast;
  const int wave = threadIdx.x >> 6, lane = threadIdx.x & 63;
  if (lane == 0) ls[wave] = s;
  __syncthreads();
  if (threadIdx.x == 0) {
    partials[(size_t)b * PB + blockIdx.x] = ls[0] + ls[1] + ls[2] + ls[3];
    __threadfence();                      // partial visible before count
    int old = atomicAdd(counter, 1);      // device-scope by default
    amLast = (old == TOTAL_BLOCKS - 1);
  }
  __syncthreads();

  if (amLast) {
    __threadfence();                      // acquire: see all partials
    double acc = 0.0;
    for (int i = threadIdx.x; i < NPART; i += NT) acc += (double)partials[i];
#pragma unroll
    for (int o = 32; o; o >>= 1) acc += __shfl_xor(acc, o);
    __shared__ double ld[4];
    if (lane == 0) ld[wave] = acc;
    __syncthreads();
    if (threadIdx.x == 0)
      out[0] = (float)((ld[0] + ld[1] + ld[2] + ld[3]) / (double)((size_t)BATCH * SPATIAL));
  }
}

extern "C" void kernel_launch(void* const* d_in, const int* in_sizes, int n_in,
                              void* d_out, int out_size, void* d_ws, size_t ws_size,
                              hipStream_t stream) {
  const float* y_pred = (const float*)d_in[0];
  const float* y_true = (const float*)d_in[1];
  const int*   mask   = (const int*)d_in[2];
  float* out = (float*)d_out;

  char* ws = (char*)d_ws;
  int*   bneg     = (int*)(ws + WS_NEG);
  int*   bmax     = (int*)(ws + WS_MAX);
  int*   counter  = (int*)(ws + WS_CNT);
  float* partials = (float*)(ws + WS_PART);

  ml_init<<<1, 64, 0, stream>>>((int*)ws);
  ml_bbox<<<dim3(PB, BATCH), NT, 0, stream>>>(mask, bneg, bmax);
  ml_loss<<<dim3(PB, BATCH), NT, 0, stream>>>(y_pred, y_true, bneg, bmax,
                                              counter, partials, out);
}

// Round 9
// 513.994 us; speedup vs baseline: 1.0152x; 1.0152x over previous
//
#include <hip/hip_runtime.h>

// MaskedLoss: mean((roi*pred - roi*true)^2), roi = expanded bbox of mask fg.
// Shapes fixed by reference: [4,1,160,160,160] fp32/fp32/int32.
//
// 3 dispatches: ml_init (tiny) -> ml_bbox (mask scan, atomic bbox reduce)
//            -> ml_loss (weighted SSE + last-block final reduction).
//
// NOTE (R8 lesson): NO nontemporal loads here. The 2-adjacent-quad access
// pattern reuses each 128B line across two instructions of the same wave;
// nt loads defeat that reuse and double HBM fetches (48->232us regression).
//
// Layout: 160^3 = 4,096,000 voxels = 1,024,000 quads (16B) per batch;
// 6400 quads per d-slice, 40 quads per (d,h) row.
// Each thread handles 2 ADJACENT quads (32 B per array) per iteration.
// Grid-stride = 1000 blocks * 256 thr * 2 quads = 512,000 quads = EXACTLY
// 80 d-slices -> along the per-thread loop d advances by 80 and (h, w) are
// LOOP-INVARIANT: no divisions, no h/w tests in the hot loops.

namespace {
constexpr int BATCH = 4;
constexpr int DSZ = 160, HSZ = 160, WSZ = 160;
constexpr int SPATIAL = DSZ * HSZ * WSZ;      // 4,096,000
constexpr int QPB = SPATIAL / 4;              // 1,024,000 quads / batch
constexpr int NT = 256;                       // 4 waves / block
constexpr int PB = 1000;                      // blocks per batch (bbox & loss)
constexpr int STRIDE_Q = PB * NT * 2;         // 512,000 quads = 80 d-slices
constexpr int ITERS = QPB / STRIDE_Q;         // 2
constexpr int DSTEP = 80;                     // d advance per iteration
constexpr int NPART = BATCH * PB;             // 4000 partials
constexpr int TOTAL_BLOCKS = BATCH * PB;      // loss-kernel block count
constexpr int SENT_MIN = 1 << 30;

// ws layout (byte offsets)
constexpr int WS_NEG = 0;      // int [4][3]: max(axis_len-1 - min) per axis
constexpr int WS_MAX = 64;     // int [4][3]: max per axis
constexpr int WS_CNT = 128;    // int: last-block counter
constexpr int WS_PART = 256;   // float [NPART]
}

typedef int   vint4   __attribute__((ext_vector_type(4)));
typedef float vfloat4 __attribute__((ext_vector_type(4)));

__device__ __forceinline__ int wred_min(int v) {
#pragma unroll
  for (int o = 32; o; o >>= 1) v = min(v, __shfl_xor(v, o));
  return v;
}
__device__ __forceinline__ int wred_max(int v) {
#pragma unroll
  for (int o = 32; o; o >>= 1) v = max(v, __shfl_xor(v, o));
  return v;
}

// ---------------- init: sentinels + counter ----------------
__global__ void ml_init(int* __restrict__ ws_i) {
  if (threadIdx.x == 0) {
#pragma unroll
    for (int k = 0; k < 12; ++k) ws_i[k] = -1;        // WS_NEG
#pragma unroll
    for (int k = 0; k < 12; ++k) ws_i[16 + k] = -1;   // WS_MAX
    ws_i[32] = 0;                                     // WS_CNT
  }
}

// ---------------- bbox: per-block fg bbox over mask, atomic global reduce ----------------
__global__ __launch_bounds__(NT) void ml_bbox(const int* __restrict__ mask,
                                              int* __restrict__ bneg,
                                              int* __restrict__ bmax) {
  const int b = blockIdx.y;
  const vint4* m4 = reinterpret_cast<const vint4*>(mask + (size_t)b * SPATIAL);

  const unsigned qb = (blockIdx.x * NT + threadIdx.x) * 2u;  // < 512000, even
  const unsigned d0 = qb / 6400u;
  const unsigned rem = qb - d0 * 6400u;                      // loop-invariant
  const unsigned h = rem / 40u;
  const int wb = (int)(rem - h * 40u) * 4;                   // 8 elems: wb..wb+7

  unsigned itermask = 0;  // bit i: any fg in iteration i (d = d0 + 80*i)
  int elemmask = 0;       // bit j: any fg at w = wb + j (any iteration), 8 bits
#pragma unroll
  for (int i = 0; i < ITERS; ++i) {
    vint4 v0 = m4[qb + (size_t)i * STRIDE_Q];
    vint4 v1 = m4[qb + (size_t)i * STRIDE_Q + 1];
    int e = (int)(v0[0] > 0) | ((int)(v0[1] > 0) << 1) |
            ((int)(v0[2] > 0) << 2) | ((int)(v0[3] > 0) << 3) |
            ((int)(v1[0] > 0) << 4) | ((int)(v1[1] > 0) << 5) |
            ((int)(v1[2] > 0) << 6) | ((int)(v1[3] > 0) << 7);
    elemmask |= e;
    itermask |= (e ? (1u << i) : 0u);
  }

  int dmin = SENT_MIN, dmax = -1, hmin = SENT_MIN, hmax = -1, wmin = SENT_MIN, wmax = -1;
  if (itermask) {
    int ifirst = __ffs(itermask) - 1;
    int ilast = 31 - __clz(itermask);
    dmin = (int)d0 + DSTEP * ifirst;
    dmax = (int)d0 + DSTEP * ilast;
    hmin = hmax = (int)h;
    wmin = wb + (__ffs(elemmask) - 1);
    wmax = wb + (31 - __clz(elemmask));
  }

  dmin = wred_min(dmin); dmax = wred_max(dmax);
  hmin = wred_min(hmin); hmax = wred_max(hmax);
  wmin = wred_min(wmin); wmax = wred_max(wmax);

  __shared__ int sred[4][6];
  const int wave = threadIdx.x >> 6, lane = threadIdx.x & 63;
  if (lane == 0) {
    sred[wave][0] = dmin; sred[wave][1] = dmax;
    sred[wave][2] = hmin; sred[wave][3] = hmax;
    sred[wave][4] = wmin; sred[wave][5] = wmax;
  }
  __syncthreads();
  if (threadIdx.x == 0) {
    int Dm = min(min(sred[0][0], sred[1][0]), min(sred[2][0], sred[3][0]));
    int DM = max(max(sred[0][1], sred[1][1]), max(sred[2][1], sred[3][1]));
    int Hm = min(min(sred[0][2], sred[1][2]), min(sred[2][2], sred[3][2]));
    int HM = max(max(sred[0][3], sred[1][3]), max(sred[2][3], sred[3][3]));
    int Wm = min(min(sred[0][4], sred[1][4]), min(sred[2][4], sred[3][4]));
    int WM = max(max(sred[0][5], sred[1][5]), max(sred[2][5], sred[3][5]));
    if (DM >= 0) {  // block saw some fg: device-scope atomic bbox reduce
      atomicMax(&bneg[b * 3 + 0], (DSZ - 1) - Dm);   // encodes min as max
      atomicMax(&bneg[b * 3 + 1], (HSZ - 1) - Hm);
      atomicMax(&bneg[b * 3 + 2], (WSZ - 1) - Wm);
      atomicMax(&bmax[b * 3 + 0], DM);
      atomicMax(&bmax[b * 3 + 1], HM);
      atomicMax(&bmax[b * 3 + 2], WM);
    }
  }
}

// replicate reference fp32 arithmetic exactly
__device__ __forceinline__ void axis_box(int mni, int mxi, int sh, int* lo_i, int* hi_i) {
  float mn = (float)mni, mx = (float)mxi;
  float c = (mx + mn) * 0.5f;
  float e = (mx - mn + 1.0f) * 0.5f * 1.2f;          // EXPAND = 1.2f
  float lo = fmaxf(0.0f, floorf(c - e));
  float hi = fminf((float)(sh - 1), floorf(c + e));  // hi is EXCLUSIVE bound
  *lo_i = (int)lo;
  *hi_i = (int)hi;
}

// ---------------- loss: weighted squared-diff + last-block final ----------------
__global__ __launch_bounds__(NT) void ml_loss(const float* __restrict__ pred,
                                              const float* __restrict__ tru,
                                              const int* __restrict__ bneg,
                                              const int* __restrict__ bmax,
                                              int* __restrict__ counter,
                                              float* __restrict__ partials,
                                              float* __restrict__ out) {
  const int b = blockIdx.y;

  // derive box params from the atomically-reduced bbox (cheap, per block)
  const int DM = bmax[b * 3 + 0], HM = bmax[b * 3 + 1], WM = bmax[b * 3 + 2];
  const int Dm = (DSZ - 1) - bneg[b * 3 + 0];
  const int Hm = (HSZ - 1) - bneg[b * 3 + 1];
  const int Wm = (WSZ - 1) - bneg[b * 3 + 2];
  int lod = 0, hid = 0, loh = 0, hih = 0, low = 0, hiw = 0;
  if (DM >= 0) {  // has fg; else empty box -> all weights 0.1
    axis_box(Dm, DM, DSZ, &lod, &hid);
    axis_box(Hm, HM, HSZ, &loh, &hih);
    axis_box(Wm, WM, WSZ, &low, &hiw);
  }

  const vfloat4* p4 = reinterpret_cast<const vfloat4*>(pred + (size_t)b * SPATIAL);
  const vfloat4* t4 = reinterpret_cast<const vfloat4*>(tru + (size_t)b * SPATIAL);

  const unsigned qb = (blockIdx.x * NT + threadIdx.x) * 2u;  // < 512000, even
  const unsigned d0 = qb / 6400u;
  const unsigned rem = qb - d0 * 6400u;                      // loop-invariant
  const unsigned h = rem / 40u;
  const int wb = (int)(rem - h * 40u) * 4;                   // 8 elems: wb..wb+7

  // fold (h,w) membership into 8 per-element weights; only the d test remains.
  const bool inh = ((int)h >= loh) & ((int)h < hih);
  float wgt[8];
#pragma unroll
  for (int j = 0; j < 8; ++j)
    wgt[j] = (inh & (wb + j >= low) & (wb + j < hiw)) ? 1.0f : 0.1f;

  float s0 = 0.0f, s1 = 0.0f, s2 = 0.0f, s3 = 0.0f;
#pragma unroll
  for (int i = 0; i < ITERS; ++i) {
    const size_t q = qb + (size_t)i * STRIDE_Q;
    vfloat4 pv0 = p4[q];
    vfloat4 pv1 = p4[q + 1];
    vfloat4 tv0 = t4[q];
    vfloat4 tv1 = t4[q + 1];
    const int d = (int)d0 + DSTEP * i;
    const bool ind = (d >= lod) & (d < hid);
    float r, a;
    r = ind ? wgt[0] : 0.1f; a = r * pv0[0] - r * tv0[0]; s0 = fmaf(a, a, s0);
    r = ind ? wgt[1] : 0.1f; a = r * pv0[1] - r * tv0[1]; s1 = fmaf(a, a, s1);
    r = ind ? wgt[2] : 0.1f; a = r * pv0[2] - r * tv0[2]; s2 = fmaf(a, a, s2);
    r = ind ? wgt[3] : 0.1f; a = r * pv0[3] - r * tv0[3]; s3 = fmaf(a, a, s3);
    r = ind ? wgt[4] : 0.1f; a = r * pv1[0] - r * tv1[0]; s0 = fmaf(a, a, s0);
    r = ind ? wgt[5] : 0.1f; a = r * pv1[1] - r * tv1[1]; s1 = fmaf(a, a, s1);
    r = ind ? wgt[6] : 0.1f; a = r * pv1[2] - r * tv1[2]; s2 = fmaf(a, a, s2);
    r = ind ? wgt[7] : 0.1f; a = r * pv1[3] - r * tv1[3]; s3 = fmaf(a, a, s3);
  }
  float s = (s0 + s1) + (s2 + s3);

#pragma unroll
  for (int o = 32; o; o >>= 1) s += __shfl_xor(s, o);
  __shared__ float ls[4];
  __shared__ bool amLast;
  const int wave = threadIdx.x >> 6, lane = threadIdx.x & 63;
  if (lane == 0) ls[wave] = s;
  __syncthreads();
  if (threadIdx.x == 0) {
    partials[(size_t)b * PB + blockIdx.x] = ls[0] + ls[1] + ls[2] + ls[3];
    __threadfence();                      // partial visible before count
    int old = atomicAdd(counter, 1);      // device-scope by default
    amLast = (old == TOTAL_BLOCKS - 1);
  }
  __syncthreads();

  if (amLast) {
    __threadfence();                      // acquire: see all partials
    double acc = 0.0;
    for (int i = threadIdx.x; i < NPART; i += NT) acc += (double)partials[i];
#pragma unroll
    for (int o = 32; o; o >>= 1) acc += __shfl_xor(acc, o);
    __shared__ double ld[4];
    if (lane == 0) ld[wave] = acc;
    __syncthreads();
    if (threadIdx.x == 0)
      out[0] = (float)((ld[0] + ld[1] + ld[2] + ld[3]) / (double)((size_t)BATCH * SPATIAL));
  }
}

extern "C" void kernel_launch(void* const* d_in, const int* in_sizes, int n_in,
                              void* d_out, int out_size, void* d_ws, size_t ws_size,
                              hipStream_t stream) {
  const float* y_pred = (const float*)d_in[0];
  const float* y_true = (const float*)d_in[1];
  const int*   mask   = (const int*)d_in[2];
  float* out = (float*)d_out;

  char* ws = (char*)d_ws;
  int*   bneg     = (int*)(ws + WS_NEG);
  int*   bmax     = (int*)(ws + WS_MAX);
  int*   counter  = (int*)(ws + WS_CNT);
  float* partials = (float*)(ws + WS_PART);

  ml_init<<<1, 64, 0, stream>>>((int*)ws);
  ml_bbox<<<dim3(PB, BATCH), NT, 0, stream>>>(mask, bneg, bmax);
  ml_loss<<<dim3(PB, BATCH), NT, 0, stream>>>(y_pred, y_true, bneg, bmax,
                                              counter, partials, out);
}

// Round 10
// 196.285 us; speedup vs baseline: 2.6583x; 2.6186x over previous
//
#include <hip/hip_runtime.h>

// MaskedLoss: mean((roi*pred - roi*true)^2), roi = expanded bbox of mask fg.
// Shapes fixed by reference: [4,1,160,160,160] fp32/fp32/int32.
//
// R10: proven R3 structure (4 dispatches, 16B/thread/iter, no atomics, no
// threadfence, no nontemporal). ONE change: pass3 grid PB 500 -> 1000
// (occupancy probe; R9 showed 74-77% occ at 4000 blocks vs 51% at 2000).
// pass1 kept byte-identical to R3 (PB=500) as an in-run control.
//
// Layout: 160^3 = 4,096,000 voxels = 1,024,000 quads per batch; 6400 quads
// per d-slice, 40 quads per (d,h) row. Strides chosen as exact multiples of
// 6400 quads so per-thread (h,w) are LOOP-INVARIANT (no divisions in loops).

namespace {
constexpr int BATCH = 4;
constexpr int DSZ = 160, HSZ = 160, WSZ = 160;
constexpr int SPATIAL = DSZ * HSZ * WSZ;      // 4,096,000
constexpr int QPB = SPATIAL / 4;              // 1,024,000 quads / batch
constexpr int NT = 256;                       // 4 waves / block

constexpr int P1B = 500;                      // pass1 blocks/batch (= R3)
constexpr int STRIDE1 = P1B * NT;             // 128,000 quads = 20 d-slices
constexpr int ITERS1 = QPB / STRIDE1;         // 8
constexpr int DSTEP1 = 20;

constexpr int P3B = 1000;                     // pass3 blocks/batch (probe)
constexpr int STRIDE3 = P3B * NT;             // 256,000 quads = 40 d-slices
constexpr int ITERS3 = QPB / STRIDE3;         // 4
constexpr int DSTEP3 = 40;

constexpr int NPART = BATCH * P3B;            // 4000 partials
constexpr int SENT_MIN = 1 << 30;
}

typedef int   vint4   __attribute__((ext_vector_type(4)));
typedef float vfloat4 __attribute__((ext_vector_type(4)));

__device__ __forceinline__ int wred_min(int v) {
#pragma unroll
  for (int o = 32; o; o >>= 1) v = min(v, __shfl_xor(v, o));
  return v;
}
__device__ __forceinline__ int wred_max(int v) {
#pragma unroll
  for (int o = 32; o; o >>= 1) v = max(v, __shfl_xor(v, o));
  return v;
}

// ---------------- pass1: per-block fg bbox over mask (branch-free) ----------------
__global__ __launch_bounds__(NT) void ml_pass1(const int* __restrict__ mask,
                                               int* __restrict__ blockres) {
  const int b = blockIdx.y;
  const vint4* m4 = reinterpret_cast<const vint4*>(mask + (size_t)b * SPATIAL);

  const unsigned q0 = blockIdx.x * NT + threadIdx.x;   // < 128000
  const unsigned d0 = q0 / 6400u;
  const unsigned rem = q0 - d0 * 6400u;                // invariant along loop
  const unsigned h = rem / 40u;
  const int wb = (int)(rem - h * 40u) * 4;

  unsigned itermask = 0;  // bit i: any fg in iteration i (d = d0 + 20*i)
  int elemmask = 0;       // bit j: any fg at w = wb + j (any iteration)
#pragma unroll
  for (int i = 0; i < ITERS1; ++i) {
    vint4 v = m4[q0 + (size_t)i * STRIDE1];
    int e = (int)(v[0] > 0) | ((int)(v[1] > 0) << 1) |
            ((int)(v[2] > 0) << 2) | ((int)(v[3] > 0) << 3);
    elemmask |= e;
    itermask |= (e ? (1u << i) : 0u);
  }

  int dmin = SENT_MIN, dmax = -1, hmin = SENT_MIN, hmax = -1, wmin = SENT_MIN, wmax = -1;
  if (itermask) {
    int ifirst = __ffs(itermask) - 1;
    int ilast = 31 - __clz(itermask);
    dmin = (int)d0 + DSTEP1 * ifirst;
    dmax = (int)d0 + DSTEP1 * ilast;
    hmin = hmax = (int)h;
    wmin = wb + (__ffs(elemmask) - 1);
    wmax = wb + (31 - __clz(elemmask));
  }

  dmin = wred_min(dmin); dmax = wred_max(dmax);
  hmin = wred_min(hmin); hmax = wred_max(hmax);
  wmin = wred_min(wmin); wmax = wred_max(wmax);

  __shared__ int sred[4][6];
  const int wave = threadIdx.x >> 6, lane = threadIdx.x & 63;
  if (lane == 0) {
    sred[wave][0] = dmin; sred[wave][1] = dmax;
    sred[wave][2] = hmin; sred[wave][3] = hmax;
    sred[wave][4] = wmin; sred[wave][5] = wmax;
  }
  __syncthreads();
  if (threadIdx.x == 0) {
    int o[6];
    o[0] = min(min(sred[0][0], sred[1][0]), min(sred[2][0], sred[3][0]));
    o[1] = max(max(sred[0][1], sred[1][1]), max(sred[2][1], sred[3][1]));
    o[2] = min(min(sred[0][2], sred[1][2]), min(sred[2][2], sred[3][2]));
    o[3] = max(max(sred[0][3], sred[1][3]), max(sred[2][3], sred[3][3]));
    o[4] = min(min(sred[0][4], sred[1][4]), min(sred[2][4], sred[3][4]));
    o[5] = max(max(sred[0][5], sred[1][5]), max(sred[2][5], sred[3][5]));
    int* dst = blockres + ((size_t)b * P1B + blockIdx.x) * 6;
#pragma unroll
    for (int k = 0; k < 6; ++k) dst[k] = o[k];
  }
}

// ---------------- pass2: reduce per-block results -> box params ----------------
__device__ __forceinline__ void axis_box(int mni, int mxi, int sh, int* lo_i, int* hi_i) {
  // replicate reference fp32 arithmetic exactly
  float mn = (float)mni, mx = (float)mxi;
  float c = (mx + mn) * 0.5f;
  float e = (mx - mn + 1.0f) * 0.5f * 1.2f;          // EXPAND = 1.2f
  float lo = fmaxf(0.0f, floorf(c - e));
  float hi = fminf((float)(sh - 1), floorf(c + e));  // hi is EXCLUSIVE bound
  *lo_i = (int)lo;
  *hi_i = (int)hi;
}

__global__ __launch_bounds__(NT) void ml_pass2(const int* __restrict__ blockres,
                                               int* __restrict__ boxp) {
  const int b = blockIdx.x;
  int dmin = SENT_MIN, dmax = -1, hmin = SENT_MIN, hmax = -1, wmin = SENT_MIN, wmax = -1;
  for (int i = threadIdx.x; i < P1B; i += NT) {
    const int* r = blockres + ((size_t)b * P1B + i) * 6;
    dmin = min(dmin, r[0]); dmax = max(dmax, r[1]);
    hmin = min(hmin, r[2]); hmax = max(hmax, r[3]);
    wmin = min(wmin, r[4]); wmax = max(wmax, r[5]);
  }

  dmin = wred_min(dmin); dmax = wred_max(dmax);
  hmin = wred_min(hmin); hmax = wred_max(hmax);
  wmin = wred_min(wmin); wmax = wred_max(wmax);

  __shared__ int sred[4][6];
  const int wave = threadIdx.x >> 6, lane = threadIdx.x & 63;
  if (lane == 0) {
    sred[wave][0] = dmin; sred[wave][1] = dmax;
    sred[wave][2] = hmin; sred[wave][3] = hmax;
    sred[wave][4] = wmin; sred[wave][5] = wmax;
  }
  __syncthreads();
  if (threadIdx.x == 0) {
    int Dm = min(min(sred[0][0], sred[1][0]), min(sred[2][0], sred[3][0]));
    int DM = max(max(sred[0][1], sred[1][1]), max(sred[2][1], sred[3][1]));
    int Hm = min(min(sred[0][2], sred[1][2]), min(sred[2][2], sred[3][2]));
    int HM = max(max(sred[0][3], sred[1][3]), max(sred[2][3], sred[3][3]));
    int Wm = min(min(sred[0][4], sred[1][4]), min(sred[2][4], sred[3][4]));
    int WM = max(max(sred[0][5], sred[1][5]), max(sred[2][5], sred[3][5]));
    int out[6];
    if (DM < 0) {  // no foreground -> empty box, all W_OUT
      out[0] = 0; out[1] = 0; out[2] = 0; out[3] = 0; out[4] = 0; out[5] = 0;
    } else {
      axis_box(Dm, DM, DSZ, &out[0], &out[1]);
      axis_box(Hm, HM, HSZ, &out[2], &out[3]);
      axis_box(Wm, WM, WSZ, &out[4], &out[5]);
    }
    int* dst = boxp + b * 8;
#pragma unroll
    for (int k = 0; k < 6; ++k) dst[k] = out[k];
  }
}

// ---------------- pass3: weighted squared-diff partial sums ----------------
__global__ __launch_bounds__(NT) void ml_pass3(const float* __restrict__ pred,
                                               const float* __restrict__ tru,
                                               const int* __restrict__ boxp,
                                               float* __restrict__ partials) {
  const int b = blockIdx.y;
  const int lod = boxp[b * 8 + 0], hid = boxp[b * 8 + 1];
  const int loh = boxp[b * 8 + 2], hih = boxp[b * 8 + 3];
  const int low = boxp[b * 8 + 4], hiw = boxp[b * 8 + 5];

  const vfloat4* p4 = reinterpret_cast<const vfloat4*>(pred + (size_t)b * SPATIAL);
  const vfloat4* t4 = reinterpret_cast<const vfloat4*>(tru + (size_t)b * SPATIAL);

  const unsigned q0 = blockIdx.x * NT + threadIdx.x;   // < 256000
  const unsigned d0 = q0 / 6400u;
  const unsigned rem = q0 - d0 * 6400u;                // invariant along loop
  const unsigned h = rem / 40u;
  const int wb = (int)(rem - h * 40u) * 4;

  // fold the (h,w) membership into per-element weights once; only the d test
  // remains in the loop.
  const bool inh = ((int)h >= loh) & ((int)h < hih);
  const float wx = (inh & (wb + 0 >= low) & (wb + 0 < hiw)) ? 1.0f : 0.1f;
  const float wy = (inh & (wb + 1 >= low) & (wb + 1 < hiw)) ? 1.0f : 0.1f;
  const float wz = (inh & (wb + 2 >= low) & (wb + 2 < hiw)) ? 1.0f : 0.1f;
  const float ww = (inh & (wb + 3 >= low) & (wb + 3 < hiw)) ? 1.0f : 0.1f;

  float s0 = 0.0f, s1 = 0.0f, s2 = 0.0f, s3 = 0.0f;
#pragma unroll
  for (int i = 0; i < ITERS3; ++i) {
    vfloat4 pv = p4[q0 + (size_t)i * STRIDE3];
    vfloat4 tv = t4[q0 + (size_t)i * STRIDE3];
    int d = (int)d0 + DSTEP3 * i;
    bool ind = (d >= lod) & (d < hid);
    float rx = ind ? wx : 0.1f;
    float ry = ind ? wy : 0.1f;
    float rz = ind ? wz : 0.1f;
    float rw = ind ? ww : 0.1f;
    float a;
    a = rx * pv[0] - rx * tv[0]; s0 = fmaf(a, a, s0);
    a = ry * pv[1] - ry * tv[1]; s1 = fmaf(a, a, s1);
    a = rz * pv[2] - rz * tv[2]; s2 = fmaf(a, a, s2);
    a = rw * pv[3] - rw * tv[3]; s3 = fmaf(a, a, s3);
  }
  float s = (s0 + s1) + (s2 + s3);

#pragma unroll
  for (int o = 32; o; o >>= 1) s += __shfl_xor(s, o);
  __shared__ float ls[4];
  const int wave = threadIdx.x >> 6, lane = threadIdx.x & 63;
  if (lane == 0) ls[wave] = s;
  __syncthreads();
  if (threadIdx.x == 0)
    partials[(size_t)b * P3B + blockIdx.x] = ls[0] + ls[1] + ls[2] + ls[3];
}

// ---------------- final: sum partials, write mean ----------------
__global__ __launch_bounds__(NT) void ml_final(const float* __restrict__ partials,
                                               float* __restrict__ out) {
  double s = 0.0;
  for (int i = threadIdx.x; i < NPART; i += NT) s += (double)partials[i];
#pragma unroll
  for (int o = 32; o; o >>= 1) s += __shfl_xor(s, o);
  __shared__ double ls[4];
  const int wave = threadIdx.x >> 6, lane = threadIdx.x & 63;
  if (lane == 0) ls[wave] = s;
  __syncthreads();
  if (threadIdx.x == 0)
    out[0] = (float)((ls[0] + ls[1] + ls[2] + ls[3]) / (double)((size_t)BATCH * SPATIAL));
}

extern "C" void kernel_launch(void* const* d_in, const int* in_sizes, int n_in,
                              void* d_out, int out_size, void* d_ws, size_t ws_size,
                              hipStream_t stream) {
  const float* y_pred = (const float*)d_in[0];
  const float* y_true = (const float*)d_in[1];
  const int*   mask   = (const int*)d_in[2];
  float* out = (float*)d_out;

  char* ws = (char*)d_ws;
  int*   blockres = (int*)(ws);                 // 4*500*6 ints = 48,000 B
  int*   boxp     = (int*)(ws + 49152);         // 4*8 ints     = 128 B
  float* partials = (float*)(ws + 53248);       // 4000 floats  = 16,000 B

  ml_pass1<<<dim3(P1B, BATCH), NT, 0, stream>>>(mask, blockres);
  ml_pass2<<<dim3(BATCH), NT, 0, stream>>>(blockres, boxp);
  ml_pass3<<<dim3(P3B, BATCH), NT, 0, stream>>>(y_pred, y_true, boxp, partials);
  ml_final<<<1, NT, 0, stream>>>(partials, out);
}